// Round 4
// baseline (258.613 us; speedup 1.0000x reference)
//
#include <hip/hip_runtime.h>

// All tensors FLOAT32 (proven R5). GEMMs: bf16 MFMA (err 0.031 < 0.108 thr).
// Interp: REVERTED to the bit-proven brute force (R0 green, 190.5us) after
// two red rounds on the MFMA-key path (R2 tripwire, R3 absmax 0.285 in the
// ballot-prefix lists; bug never located -> abandoned per rigor discipline).
// Improvement kept this round: 4 targets per lane (amortizes src load + idx +
// loop overhead: ~40 -> ~26 lane-ops/pair; exact-rn d2, strict-< insertion,
// ascending-chunk merges -> selection bit-identical to R0). BN stats are
// deterministic per-rowblock partials reduced in fixed order (zero atomics
// anywhere -> graph-vs-direct bitwise identical; removes R2's tripwire risk).

typedef __attribute__((ext_vector_type(8))) short bf16x8;
typedef __attribute__((ext_vector_type(4))) float f32x4;

__device__ __forceinline__ unsigned short f2bf(float f) {
    union { float f; unsigned u; } v; v.f = f;
    return (unsigned short)((v.u + 0x7fffu + ((v.u >> 16) & 1u)) >> 16); // RNE
}
__device__ __forceinline__ unsigned pack2(float a, float b) {
    return (unsigned)f2bf(a) | ((unsigned)f2bf(b) << 16);
}

// ---------- prep: xyz -> padded float4 ----------
__global__ __launch_bounds__(256)
void prep_kernel(const float* __restrict__ p1, const float* __restrict__ p2,
                 const float* __restrict__ p4,
                 float4* __restrict__ x1, float4* __restrict__ x2,
                 float4* __restrict__ x4) {
    int i = blockIdx.x * 256 + threadIdx.x;
    const int P1 = 16384, P2 = 8192, P4 = 4096;
    if (i < P1) {
        x1[i] = make_float4(p1[i*3], p1[i*3+1], p1[i*3+2], 0.f);
    } else if (i < P1 + P2) {
        int j = i - P1;
        x2[j] = make_float4(p2[j*3], p2[j*3+1], p2[j*3+2], 0.f);
    } else if (i < P1 + P2 + P4) {
        int j = i - P1 - P2;
        x4[j] = make_float4(p4[j*3], p4[j*3+1], p4[j*3+2], 0.f);
    }
}

// ---------- 3-NN interpolate: brute force, 4 targets/lane ----------
// Block: 256 thr = 2 target-groups(4 tgt each) x 128 chunks. 8 targets/block.
// Exact rn d2 ((dx2+dy2)+dz2, no FMA); strict-< insertion + ascending
// enumeration (thread chunk ascending, L1 merges 8 chunks ascending, L2
// merges 16 partials ascending) == lax.top_k stable tie-break (R0-proven).
template<int CHUNK>
__global__ __launch_bounds__(256)
void nn_interp_kernel(const float4* __restrict__ tgt, int Nt,
                      const float4* __restrict__ src, int Ns,
                      const float* __restrict__ feats,
                      float* __restrict__ out) {
    int tid = threadIdx.x;
    int ch = tid & 127;           // 128 chunks
    int tg = tid >> 7;            // 2 target groups of 4
    int b = blockIdx.y;
    int tbase = blockIdx.x * 8;

    float4 tv0 = tgt[b * Nt + tbase + tg * 4 + 0];
    float4 tv1 = tgt[b * Nt + tbase + tg * 4 + 1];
    float4 tv2 = tgt[b * Nt + tbase + tg * 4 + 2];
    float4 tv3 = tgt[b * Nt + tbase + tg * 4 + 3];
    float txr[4] = {tv0.x, tv1.x, tv2.x, tv3.x};
    float tyr[4] = {tv0.y, tv1.y, tv2.y, tv3.y};
    float tzr[4] = {tv0.z, tv1.z, tv2.z, tv3.z};

    float a0[4], a1[4], a2[4];
    int ia0[4], ia1[4], ia2[4];
    #pragma unroll
    for (int k = 0; k < 4; ++k) {
        a0[k] = 3.4e38f; a1[k] = 3.4e38f; a2[k] = 3.4e38f;
        ia0[k] = 0; ia1[k] = 0; ia2[k] = 0;
    }

    const float4* sp = src + b * Ns + ch * CHUNK;
    #pragma unroll 4
    for (int j = 0; j < CHUNK; ++j) {
        float4 s = sp[j];
        int idx = ch * CHUNK + j;
        #pragma unroll
        for (int k = 0; k < 4; ++k) {
            float dx = txr[k] - s.x, dy = tyr[k] - s.y, dz = tzr[k] - s.z;
            float d2 = __fadd_rn(__fadd_rn(__fmul_rn(dx,dx), __fmul_rn(dy,dy)),
                                 __fmul_rn(dz,dz));
            bool c0 = d2 < a0[k], c1 = d2 < a1[k], c2 = d2 < a2[k];
            float na2 = fminf(a2[k], fmaxf(a1[k], d2));
            float na1 = __builtin_amdgcn_fmed3f(a0[k], a1[k], d2);
            float na0 = fminf(a0[k], d2);
            ia2[k] = c1 ? ia1[k] : (c2 ? idx : ia2[k]);
            ia1[k] = c0 ? ia0[k] : (c1 ? idx : ia1[k]);
            ia0[k] = c0 ? idx : ia0[k];
            a0[k] = na0; a1[k] = na1; a2[k] = na2;
        }
    }

    __shared__ float          sd[8][128][3];
    __shared__ unsigned short si[8][128][3];   // idx < 4096 fits ushort
    __shared__ float          pd[8][16][3];
    __shared__ unsigned short pi[8][16][3];
    __shared__ float sw[8][3];
    __shared__ int   sg[8][3];

    #pragma unroll
    for (int k = 0; k < 4; ++k) {
        sd[tg*4+k][ch][0] = a0[k]; sd[tg*4+k][ch][1] = a1[k]; sd[tg*4+k][ch][2] = a2[k];
        si[tg*4+k][ch][0] = (unsigned short)ia0[k];
        si[tg*4+k][ch][1] = (unsigned short)ia1[k];
        si[tg*4+k][ch][2] = (unsigned short)ia2[k];
    }
    __syncthreads();

    // level 1: 128 threads = 8 targets x 16 mergers; each merges 8 chunks asc
    if (tid < 128) {
        int tt = tid >> 4, m = tid & 15;
        float m0 = 3.4e38f, m1 = 3.4e38f, m2 = 3.4e38f;
        int j0 = 0, j1 = 0, j2 = 0;
        #pragma unroll
        for (int cc = m * 8; cc < m * 8 + 8; ++cc) {
            #pragma unroll
            for (int k = 0; k < 3; ++k) {
                float d = sd[tt][cc][k]; int ix = si[tt][cc][k];
                bool c0 = d < m0, c1 = d < m1, c2 = d < m2;
                m2 = c1 ? m1 : (c2 ? d : m2);  j2 = c1 ? j1 : (c2 ? ix : j2);
                m1 = c0 ? m0 : (c1 ? d : m1);  j1 = c0 ? j0 : (c1 ? ix : j1);
                m0 = c0 ? d : m0;              j0 = c0 ? ix : j0;
            }
        }
        pd[tt][m][0] = m0; pd[tt][m][1] = m1; pd[tt][m][2] = m2;
        pi[tt][m][0] = (unsigned short)j0;
        pi[tt][m][1] = (unsigned short)j1;
        pi[tt][m][2] = (unsigned short)j2;
    }
    __syncthreads();

    // level 2: 8 threads merge 16 partials ascending, compute weights
    if (tid < 8) {
        float m0 = 3.4e38f, m1 = 3.4e38f, m2 = 3.4e38f;
        int j0 = 0, j1 = 0, j2 = 0;
        #pragma unroll
        for (int m = 0; m < 16; ++m) {
            #pragma unroll
            for (int k = 0; k < 3; ++k) {
                float d = pd[tid][m][k]; int ix = pi[tid][m][k];
                bool c0 = d < m0, c1 = d < m1, c2 = d < m2;
                m2 = c1 ? m1 : (c2 ? d : m2);  j2 = c1 ? j1 : (c2 ? ix : j2);
                m1 = c0 ? m0 : (c1 ? d : m1);  j1 = c0 ? j0 : (c1 ? ix : j1);
                m0 = c0 ? d : m0;              j0 = c0 ? ix : j0;
            }
        }
        float d0 = sqrtf(fmaxf(m0, 0.f));
        float d1 = sqrtf(fmaxf(m1, 0.f));
        float d2 = sqrtf(fmaxf(m2, 0.f));
        float w0 = 1.f / (d0 + 1e-8f);
        float w1 = 1.f / (d1 + 1e-8f);
        float w2 = 1.f / (d2 + 1e-8f);
        float wsum = w0 + w1 + w2;
        sw[tid][0] = w0 / wsum; sw[tid][1] = w1 / wsum; sw[tid][2] = w2 / wsum;
        sg[tid][0] = j0; sg[tid][1] = j1; sg[tid][2] = j2;
    }
    __syncthreads();

    // gather: 8 targets x 64 channel-pairs
    for (int e = tid; e < 8 * 64; e += 256) {
        int tt = e >> 6, cp = (e & 63) * 2;
        int base = b * Ns * 128;
        float2 f0  = *(const float2*)&feats[base + sg[tt][0] * 128 + cp];
        float2 f1  = *(const float2*)&feats[base + sg[tt][1] * 128 + cp];
        float2 f2v = *(const float2*)&feats[base + sg[tt][2] * 128 + cp];
        float2 o;
        o.x = sw[tt][0] * f0.x + sw[tt][1] * f1.x + sw[tt][2] * f2v.x;
        o.y = sw[tt][0] * f0.y + sw[tt][1] * f1.y + sw[tt][2] * f2v.y;
        *(float2*)&out[(b * Nt + tbase + tt) * 128 + cp] = o;
    }
}

// ---------- GEMM A (MFMA bf16, + per-rowblock BN partials): H = [L|R] @ W^T ----------
__global__ __launch_bounds__(256)
void gemm_a_kernel(const float* __restrict__ L, const float* __restrict__ R,
                   const float* __restrict__ W, float* __restrict__ H,
                   float* __restrict__ stp) {
    __shared__ short Asm[4096];
    __shared__ short Bsm[2048];
    int tid = threadIdx.x;
    int lane = tid & 63, w = tid >> 6;
    int m16 = lane & 15, quad = lane >> 4;
    int rowBase = blockIdx.y * 128;
    int colBase = blockIdx.x * 64;
    f32x4 acc[2][4] = {};
    for (int k0 = 0; k0 < 256; k0 += 32) {
        #pragma unroll
        for (int i = 0; i < 2; ++i) {
            int u = tid + i * 256;
            int r = u >> 2, g = u & 3;
            const float* p = (k0 < 128) ? &L[(rowBase + r) * 128 + k0 + g * 8]
                                        : &R[(rowBase + r) * 128 + (k0 - 128) + g * 8];
            float4 x = *(const float4*)p, y = *(const float4*)(p + 4);
            uint4 pk = make_uint4(pack2(x.x, x.y), pack2(x.z, x.w),
                                  pack2(y.x, y.y), pack2(y.z, y.w));
            int blk = (r >> 4) * 64 + (r & 15) * 4 + g;
            *(uint4*)&Asm[blk * 8] = pk;
        }
        {
            int n = tid >> 2, g = tid & 3;
            const float* p = &W[(colBase + n) * 256 + k0 + g * 8];
            float4 x = *(const float4*)p, y = *(const float4*)(p + 4);
            uint4 pk = make_uint4(pack2(x.x, x.y), pack2(x.z, x.w),
                                  pack2(y.x, y.y), pack2(y.z, y.w));
            int blk = (n >> 4) * 64 + (n & 15) * 4 + g;
            *(uint4*)&Bsm[blk * 8] = pk;
        }
        __syncthreads();
        bf16x8 a0 = *(const bf16x8*)&Asm[((2 * w + 0) * 64 + m16 * 4 + quad) * 8];
        bf16x8 a1 = *(const bf16x8*)&Asm[((2 * w + 1) * 64 + m16 * 4 + quad) * 8];
        #pragma unroll
        for (int ct = 0; ct < 4; ++ct) {
            bf16x8 bf = *(const bf16x8*)&Bsm[(ct * 64 + m16 * 4 + quad) * 8];
            acc[0][ct] = __builtin_amdgcn_mfma_f32_16x16x32_bf16(a0, bf, acc[0][ct], 0, 0, 0);
            acc[1][ct] = __builtin_amdgcn_mfma_f32_16x16x32_bf16(a1, bf, acc[1][ct], 0, 0, 0);
        }
        __syncthreads();
    }
    #pragma unroll
    for (int rt = 0; rt < 2; ++rt)
        #pragma unroll
        for (int r = 0; r < 4; ++r) {
            int row = rowBase + (2 * w + rt) * 16 + quad * 4 + r;
            #pragma unroll
            for (int ct = 0; ct < 4; ++ct)
                H[row * 128 + colBase + ct * 16 + m16] = acc[rt][ct][r];
        }
    float* ssum = (float*)Asm;
    float* ssq  = (float*)Asm + 1024;
    #pragma unroll
    for (int ct = 0; ct < 4; ++ct) {
        float s = 0.f, q = 0.f;
        #pragma unroll
        for (int rt = 0; rt < 2; ++rt)
            #pragma unroll
            for (int r = 0; r < 4; ++r) {
                float v = acc[rt][ct][r];
                s += v; q += v * v;
            }
        ssum[(w * 4 + quad) * 64 + ct * 16 + m16] = s;
        ssq [(w * 4 + quad) * 64 + ct * 16 + m16] = q;
    }
    __syncthreads();
    if (tid < 64) {
        float s = 0.f, q = 0.f;
        #pragma unroll
        for (int i = 0; i < 16; ++i) { s += ssum[i * 64 + tid]; q += ssq[i * 64 + tid]; }
        // deterministic per-rowblock partials (no atomics)
        stp[blockIdx.y * 256 + colBase + tid] = s;
        stp[blockIdx.y * 256 + 128 + colBase + tid] = q;
    }
}

// ---------- GEMM B (MFMA bf16, BN finalize fused; ordered partial reduce) ----------
__global__ __launch_bounds__(256)
void gemm_b_kernel(const float* __restrict__ Hin, const float* __restrict__ stp,
                   int NR, const float* __restrict__ gam, const float* __restrict__ bet,
                   float invN, const float* __restrict__ W,
                   const float* __restrict__ bias, float* __restrict__ out) {
    __shared__ short Asm[4096];
    __shared__ short Bsm[2048];
    __shared__ float ssc[128], ssf[128];
    int tid = threadIdx.x;
    if (tid < 128) {
        float s = 0.f, q = 0.f;
        for (int r = 0; r < NR; ++r) {          // fixed order -> deterministic
            s += stp[r * 256 + tid];
            q += stp[r * 256 + 128 + tid];
        }
        float mu = s * invN;
        float var = q * invN - mu * mu;
        float rstd = rsqrtf(fmaxf(var, 0.f) + 1e-5f);
        float sc = rstd * gam[tid];
        ssc[tid] = sc;
        ssf[tid] = bet[tid] - mu * sc;
    }
    __syncthreads();
    int lane = tid & 63, w = tid >> 6;
    int m16 = lane & 15, quad = lane >> 4;
    int rowBase = blockIdx.y * 128;
    int colBase = blockIdx.x * 64;
    f32x4 acc[2][4] = {};
    for (int k0 = 0; k0 < 128; k0 += 32) {
        #pragma unroll
        for (int i = 0; i < 2; ++i) {
            int u = tid + i * 256;
            int r = u >> 2, g = u & 3;
            int c = k0 + g * 8;
            const float* p = &Hin[(rowBase + r) * 128 + c];
            float4 x = *(const float4*)p, y = *(const float4*)(p + 4);
            float h0 = fmaxf(x.x * ssc[c+0] + ssf[c+0], 0.f);
            float h1 = fmaxf(x.y * ssc[c+1] + ssf[c+1], 0.f);
            float h2 = fmaxf(x.z * ssc[c+2] + ssf[c+2], 0.f);
            float h3 = fmaxf(x.w * ssc[c+3] + ssf[c+3], 0.f);
            float h4 = fmaxf(y.x * ssc[c+4] + ssf[c+4], 0.f);
            float h5 = fmaxf(y.y * ssc[c+5] + ssf[c+5], 0.f);
            float h6 = fmaxf(y.z * ssc[c+6] + ssf[c+6], 0.f);
            float h7 = fmaxf(y.w * ssc[c+7] + ssf[c+7], 0.f);
            uint4 pk = make_uint4(pack2(h0, h1), pack2(h2, h3),
                                  pack2(h4, h5), pack2(h6, h7));
            int blk = (r >> 4) * 64 + (r & 15) * 4 + g;
            *(uint4*)&Asm[blk * 8] = pk;
        }
        {
            int n = tid >> 2, g = tid & 3;
            const float* p = &W[(colBase + n) * 128 + k0 + g * 8];
            float4 x = *(const float4*)p, y = *(const float4*)(p + 4);
            uint4 pk = make_uint4(pack2(x.x, x.y), pack2(x.z, x.w),
                                  pack2(y.x, y.y), pack2(y.z, y.w));
            int blk = (n >> 4) * 64 + (n & 15) * 4 + g;
            *(uint4*)&Bsm[blk * 8] = pk;
        }
        __syncthreads();
        bf16x8 a0 = *(const bf16x8*)&Asm[((2 * w + 0) * 64 + m16 * 4 + quad) * 8];
        bf16x8 a1 = *(const bf16x8*)&Asm[((2 * w + 1) * 64 + m16 * 4 + quad) * 8];
        #pragma unroll
        for (int ct = 0; ct < 4; ++ct) {
            bf16x8 bf = *(const bf16x8*)&Bsm[(ct * 64 + m16 * 4 + quad) * 8];
            acc[0][ct] = __builtin_amdgcn_mfma_f32_16x16x32_bf16(a0, bf, acc[0][ct], 0, 0, 0);
            acc[1][ct] = __builtin_amdgcn_mfma_f32_16x16x32_bf16(a1, bf, acc[1][ct], 0, 0, 0);
        }
        __syncthreads();
    }
    #pragma unroll
    for (int ct = 0; ct < 4; ++ct) {
        float bv = bias[colBase + ct * 16 + m16];
        #pragma unroll
        for (int rt = 0; rt < 2; ++rt)
            #pragma unroll
            for (int r = 0; r < 4; ++r) {
                int row = rowBase + (2 * w + rt) * 16 + quad * 4 + r;
                out[row * 128 + colBase + ct * 16 + m16] = acc[rt][ct][r] + bv;
            }
    }
}

extern "C" void kernel_launch(void* const* d_in, const int* in_sizes, int n_in,
                              void* d_out, int out_size, void* d_ws, size_t ws_size,
                              hipStream_t stream) {
    const float* pts_r1 = (const float*)d_in[0];   // (2,8192,3)
    const float* pts_r2 = (const float*)d_in[1];   // (2,4096,3)
    const float* pts_r4 = (const float*)d_in[2];   // (2,2048,3)
    const float* feat0  = (const float*)d_in[3];   // (16384,128)
    const float* feat1  = (const float*)d_in[4];   // (8192,128)
    const float* feat2  = (const float*)d_in[5];   // (4096,128)
    const float* w3a = (const float*)d_in[6];      // (128,256)
    const float* g3  = (const float*)d_in[7];
    const float* b3  = (const float*)d_in[8];
    const float* w3b = (const float*)d_in[9];      // (128,128)
    const float* bb3 = (const float*)d_in[10];
    const float* w4a = (const float*)d_in[11];     // (128,256)
    const float* g4  = (const float*)d_in[12];
    const float* b4  = (const float*)d_in[13];
    const float* w4b = (const float*)d_in[14];     // (128,128)
    const float* bb4 = (const float*)d_in[15];

    float* wsf = (float*)d_ws;
    float4* xyz1 = (float4*)(wsf + 0);        // [0, 65536)
    float4* xyz2 = (float4*)(wsf + 65536);    // [65536, 98304)
    float4* xyz4 = (float4*)(wsf + 98304);    // [98304, 114688)
    float* f2i = wsf + 114688;                // [114688, 1163264)
    float* H1  = wsf + 1163264;               // [1163264, 2211840)
    float* n3  = wsf + 2211840;               // [2211840, 3260416)
    float* n3i = wsf + 114688;                // [114688, 2211840) over f2i+H1 (dead)
    float* H2  = wsf + 3260416;               // [3260416, 5357568)
    // BN partials (no atomics): st1p in H2 head (dead until gemm_a_f4 writes
    // H2, consumed by gemm_b_f3 before that); st2p over n3 head (n3 dead
    // after interp2, written by gemm_a_f4 which runs after interp2).
    float* st1p = wsf + 3260416;              // 64*256  = [3260416, 3276800)
    float* st2p = wsf + 2211840;              // 128*256 = [2211840, 2244608)

    // 1. prep: pad xyz
    prep_kernel<<<112, 256, 0, stream>>>(pts_r1, pts_r2, pts_r4, xyz1, xyz2, xyz4);
    // 2. interp #1: feat2 (pts_r4 grid, Ns=2048) -> pts_r2 targets; CHUNK=16
    nn_interp_kernel<16><<<dim3(512, 2), 256, 0, stream>>>(xyz2, 4096, xyz4, 2048,
                                                           feat2, f2i);
    // 3. fnode 3
    gemm_a_kernel<<<dim3(2, 64), 256, 0, stream>>>(feat1, f2i, w3a, H1, st1p);
    gemm_b_kernel<<<dim3(2, 64), 256, 0, stream>>>(H1, st1p, 64, g3, b3,
                                                   1.f / 8192.f, w3b, bb3, n3);
    // 4. interp #2: n3 (pts_r2 grid, Ns=4096) -> pts_r1 targets; CHUNK=32
    nn_interp_kernel<32><<<dim3(1024, 2), 256, 0, stream>>>(xyz1, 8192, xyz2, 4096,
                                                            n3, n3i);
    // 5. fnode 4
    gemm_a_kernel<<<dim3(2, 128), 256, 0, stream>>>(feat0, n3i, w4a, H2, st2p);
    gemm_b_kernel<<<dim3(2, 128), 256, 0, stream>>>(H2, st2p, 128, g4, b4,
                                                    1.f / 16384.f, w4b, bb4,
                                                    (float*)d_out);
}

// Round 5
// 225.093 us; speedup vs baseline: 1.1489x; 1.1489x over previous
//
#include <hip/hip_runtime.h>

// All tensors FLOAT32 in/out (proven R5). GEMMs: bf16 MFMA (err 0.031 < 0.108).
// Interp: EXACT R0 brute-force scan/merge/selection (proven 45.3us green; R1/R4
// restructures both regressed -> shape is locally optimal, do not touch).
// This round: hoist all fp32->bf16 RNE conversion out of the GEMM hot loops.
//  - prep converts feat0/feat1/w3a/w4a/w3b/w4b to bf16 once (same f2bf RNE).
//  - interp writes its output directly as bf16 RNE (identical value to what
//    gemm_a's pack2 produced before) -> every MFMA input is BIT-IDENTICAL to
//    the 190.5us baseline; interp gathers still read fp32 sources.
//  - gemm_a staging = pure uint4 copies (was ~120 VALU/thread/K-step).
//  - feat0's bf16 copy is staged in d_out (dead until final gemm writes it).
// BN stats: deterministic per-rowblock partials, fixed-order reduce (R4-green,
// zero atomics anywhere -> graph-vs-direct bitwise identical).

typedef __attribute__((ext_vector_type(8))) short bf16x8;
typedef __attribute__((ext_vector_type(4))) float f32x4;

__device__ __forceinline__ unsigned short f2bf(float f) {
    union { float f; unsigned u; } v; v.f = f;
    return (unsigned short)((v.u + 0x7fffu + ((v.u >> 16) & 1u)) >> 16); // RNE
}
__device__ __forceinline__ unsigned pack2(float a, float b) {
    return (unsigned)f2bf(a) | ((unsigned)f2bf(b) << 16);
}

// ---------- prep: xyz -> padded float4; bf16 pre-conversion ----------
__global__ __launch_bounds__(256)
void prep_kernel(const float* __restrict__ p1, const float* __restrict__ p2,
                 const float* __restrict__ p4,
                 const float* __restrict__ f0, const float* __restrict__ f1,
                 const float* __restrict__ w3a, const float* __restrict__ w4a,
                 const float* __restrict__ w3b, const float* __restrict__ w4b,
                 float4* __restrict__ x1, float4* __restrict__ x2,
                 float4* __restrict__ x4,
                 unsigned* __restrict__ f0b, unsigned* __restrict__ f1b,
                 unsigned* __restrict__ w3ab, unsigned* __restrict__ w4ab,
                 unsigned* __restrict__ w3bb, unsigned* __restrict__ w4bb) {
    int i = blockIdx.x * 256 + threadIdx.x;
    const int P1 = 16384, P2 = 8192, P4 = 4096;
    if (i < P1) {
        x1[i] = make_float4(p1[i*3], p1[i*3+1], p1[i*3+2], 0.f);
    } else if (i < P1 + P2) {
        int j = i - P1;
        x2[j] = make_float4(p2[j*3], p2[j*3+1], p2[j*3+2], 0.f);
    } else if (i < P1 + P2 + P4) {
        int j = i - P1 - P2;
        x4[j] = make_float4(p4[j*3], p4[j*3+1], p4[j*3+2], 0.f);
    }
    // grid-stride bf16 conversion (pairs of floats -> one u32 of 2 bf16)
    const int F0P = 1048576, F1P = 524288, WAP = 16384, WBP = 8192;
    const int TOT = F0P + F1P + WAP + WAP + WBP + WBP;   // 1,622,016 pairs
    const int NT = gridDim.x * 256;
    for (int p = i; p < TOT; p += NT) {
        const float* s; unsigned* d; int q = p;
        if (q < F0P)                { s = f0;  d = f0b;  }
        else if ((q -= F0P) < F1P)  { s = f1;  d = f1b;  }
        else if ((q -= F1P) < WAP)  { s = w3a; d = w3ab; }
        else if ((q -= WAP) < WAP)  { s = w4a; d = w4ab; }
        else if ((q -= WAP) < WBP)  { s = w3b; d = w3bb; }
        else       { q -= WBP;        s = w4b; d = w4bb; }
        float2 v = *(const float2*)(s + (size_t)q * 2);
        d[q] = pack2(v.x, v.y);
    }
}

// ---------- 3-NN interpolate (R0-exact scan/merge/selection) ----------
// 8 targets x 32 chunks; exact rn d2; strict-< insertion + ascending
// enumeration == lax.top_k stable tie-break. Only change vs R0: the gather
// stores bf16 RNE (bit-identical to downstream gemm's former conversion).
template<int CHUNK>
__global__ __launch_bounds__(256)
void nn_interp_kernel(const float4* __restrict__ tgt, int Nt,
                      const float4* __restrict__ src, int Ns,
                      const float* __restrict__ feats,
                      unsigned* __restrict__ out) {
    int tid = threadIdx.x;
    int pl = tid & 7, ch = tid >> 3;
    int b = blockIdx.y;
    int tbase = blockIdx.x * 8;
    float4 ta = tgt[b * Nt + tbase + pl];

    float a0=3.4e38f, a1=3.4e38f, a2=3.4e38f;
    int ia0=0, ia1=0, ia2=0;
    const float4* sp = src + b * Ns + ch * CHUNK;
    #pragma unroll 8
    for (int j = 0; j < CHUNK; ++j) {
        float4 s = sp[j];
        int idx = ch * CHUNK + j;
        float dx = ta.x - s.x, dy = ta.y - s.y, dz = ta.z - s.z;
        float d2 = __fadd_rn(__fadd_rn(__fmul_rn(dx,dx), __fmul_rn(dy,dy)),
                             __fmul_rn(dz,dz));
        bool c0 = d2 < a0, c1 = d2 < a1, c2 = d2 < a2;
        float na2 = fminf(a2, fmaxf(a1, d2));
        float na1 = __builtin_amdgcn_fmed3f(a0, a1, d2);
        float na0 = fminf(a0, d2);
        ia2 = c1 ? ia1 : (c2 ? idx : ia2);
        ia1 = c0 ? ia0 : (c1 ? idx : ia1);
        ia0 = c0 ? idx : ia0;
        a0 = na0; a1 = na1; a2 = na2;
    }

    __shared__ float sd[8][32][3];
    __shared__ int   si[8][32][3];
    __shared__ float pd[8][4][3];
    __shared__ int   pi[8][4][3];
    __shared__ float sw[8][3];
    __shared__ int   sg[8][3];
    sd[pl][ch][0]=a0; sd[pl][ch][1]=a1; sd[pl][ch][2]=a2;
    si[pl][ch][0]=ia0; si[pl][ch][1]=ia1; si[pl][ch][2]=ia2;
    __syncthreads();

    // level 1: 32 threads = 8 targets x 4 mergers; each merges 8 chunks asc
    if (tid < 32) {
        int tt = tid >> 2, m = tid & 3;
        float m0=3.4e38f, m1=3.4e38f, m2=3.4e38f;
        int j0=0, j1=0, j2=0;
        #pragma unroll
        for (int cc = m * 8; cc < m * 8 + 8; ++cc) {
            #pragma unroll
            for (int k = 0; k < 3; ++k) {
                float d = sd[tt][cc][k]; int ix = si[tt][cc][k];
                bool c0 = d < m0, c1 = d < m1, c2 = d < m2;
                m2 = c1 ? m1 : (c2 ? d : m2);  j2 = c1 ? j1 : (c2 ? ix : j2);
                m1 = c0 ? m0 : (c1 ? d : m1);  j1 = c0 ? j0 : (c1 ? ix : j1);
                m0 = c0 ? d : m0;              j0 = c0 ? ix : j0;
            }
        }
        pd[tt][m][0]=m0; pd[tt][m][1]=m1; pd[tt][m][2]=m2;
        pi[tt][m][0]=j0; pi[tt][m][1]=j1; pi[tt][m][2]=j2;
    }
    __syncthreads();

    // level 2: 8 threads merge 4 partials ascending, compute weights
    if (tid < 8) {
        float m0=3.4e38f, m1=3.4e38f, m2=3.4e38f;
        int j0=0, j1=0, j2=0;
        #pragma unroll
        for (int m = 0; m < 4; ++m) {
            #pragma unroll
            for (int k = 0; k < 3; ++k) {
                float d = pd[tid][m][k]; int ix = pi[tid][m][k];
                bool c0 = d < m0, c1 = d < m1, c2 = d < m2;
                m2 = c1 ? m1 : (c2 ? d : m2);  j2 = c1 ? j1 : (c2 ? ix : j2);
                m1 = c0 ? m0 : (c1 ? d : m1);  j1 = c0 ? j0 : (c1 ? ix : j1);
                m0 = c0 ? d : m0;              j0 = c0 ? ix : j0;
            }
        }
        float d0 = sqrtf(fmaxf(m0, 0.f));
        float d1 = sqrtf(fmaxf(m1, 0.f));
        float d2 = sqrtf(fmaxf(m2, 0.f));
        float w0 = 1.f / (d0 + 1e-8f);
        float w1 = 1.f / (d1 + 1e-8f);
        float w2 = 1.f / (d2 + 1e-8f);
        float wsum = w0 + w1 + w2;
        sw[tid][0] = w0 / wsum; sw[tid][1] = w1 / wsum; sw[tid][2] = w2 / wsum;
        sg[tid][0] = j0; sg[tid][1] = j1; sg[tid][2] = j2;
    }
    __syncthreads();

    // gather: 8 targets x 64 channel-pairs; store bf16 RNE pair as u32
    for (int e = tid; e < 8 * 64; e += 256) {
        int tt = e >> 6, cp = (e & 63) * 2;
        int base = b * Ns * 128;
        float2 f0  = *(const float2*)&feats[base + sg[tt][0] * 128 + cp];
        float2 f1  = *(const float2*)&feats[base + sg[tt][1] * 128 + cp];
        float2 f2v = *(const float2*)&feats[base + sg[tt][2] * 128 + cp];
        float ox = sw[tt][0] * f0.x + sw[tt][1] * f1.x + sw[tt][2] * f2v.x;
        float oy = sw[tt][0] * f0.y + sw[tt][1] * f1.y + sw[tt][2] * f2v.y;
        out[(b * Nt + tbase + tt) * 64 + (cp >> 1)] = pack2(ox, oy);
    }
}

// ---------- GEMM A (bf16 inputs, pure-copy staging, BN partials) ----------
// H = [L|R] @ W^T ; L,R,W pre-converted bf16 -> staging is uint4 copies.
__global__ __launch_bounds__(256)
void gemm_a_kernel(const unsigned short* __restrict__ Lb,
                   const unsigned short* __restrict__ Rb,
                   const unsigned short* __restrict__ Wb,
                   float* __restrict__ H, float* __restrict__ stp) {
    __shared__ short Asm[4096];
    __shared__ short Bsm[2048];
    int tid = threadIdx.x;
    int lane = tid & 63, w = tid >> 6;
    int m16 = lane & 15, quad = lane >> 4;
    int rowBase = blockIdx.y * 128;
    int colBase = blockIdx.x * 64;
    f32x4 acc[2][4] = {};
    for (int k0 = 0; k0 < 256; k0 += 32) {
        #pragma unroll
        for (int i = 0; i < 2; ++i) {
            int u = tid + i * 256;
            int r = u >> 2, g = u & 3;
            const unsigned short* p = (k0 < 128)
                ? &Lb[(size_t)(rowBase + r) * 128 + k0 + g * 8]
                : &Rb[(size_t)(rowBase + r) * 128 + (k0 - 128) + g * 8];
            uint4 pk = *(const uint4*)p;
            int blk = (r >> 4) * 64 + (r & 15) * 4 + g;
            *(uint4*)&Asm[blk * 8] = pk;
        }
        {
            int n = tid >> 2, g = tid & 3;
            uint4 pk = *(const uint4*)&Wb[(size_t)(colBase + n) * 256 + k0 + g * 8];
            int blk = (n >> 4) * 64 + (n & 15) * 4 + g;
            *(uint4*)&Bsm[blk * 8] = pk;
        }
        __syncthreads();
        bf16x8 a0 = *(const bf16x8*)&Asm[((2 * w + 0) * 64 + m16 * 4 + quad) * 8];
        bf16x8 a1 = *(const bf16x8*)&Asm[((2 * w + 1) * 64 + m16 * 4 + quad) * 8];
        #pragma unroll
        for (int ct = 0; ct < 4; ++ct) {
            bf16x8 bf = *(const bf16x8*)&Bsm[(ct * 64 + m16 * 4 + quad) * 8];
            acc[0][ct] = __builtin_amdgcn_mfma_f32_16x16x32_bf16(a0, bf, acc[0][ct], 0, 0, 0);
            acc[1][ct] = __builtin_amdgcn_mfma_f32_16x16x32_bf16(a1, bf, acc[1][ct], 0, 0, 0);
        }
        __syncthreads();
    }
    #pragma unroll
    for (int rt = 0; rt < 2; ++rt)
        #pragma unroll
        for (int r = 0; r < 4; ++r) {
            int row = rowBase + (2 * w + rt) * 16 + quad * 4 + r;
            #pragma unroll
            for (int ct = 0; ct < 4; ++ct)
                H[row * 128 + colBase + ct * 16 + m16] = acc[rt][ct][r];
        }
    float* ssum = (float*)Asm;
    float* ssq  = (float*)Asm + 1024;
    #pragma unroll
    for (int ct = 0; ct < 4; ++ct) {
        float s = 0.f, q = 0.f;
        #pragma unroll
        for (int rt = 0; rt < 2; ++rt)
            #pragma unroll
            for (int r = 0; r < 4; ++r) {
                float v = acc[rt][ct][r];
                s += v; q += v * v;
            }
        ssum[(w * 4 + quad) * 64 + ct * 16 + m16] = s;
        ssq [(w * 4 + quad) * 64 + ct * 16 + m16] = q;
    }
    __syncthreads();
    if (tid < 64) {
        float s = 0.f, q = 0.f;
        #pragma unroll
        for (int i = 0; i < 16; ++i) { s += ssum[i * 64 + tid]; q += ssq[i * 64 + tid]; }
        // deterministic per-rowblock partials (no atomics)
        stp[blockIdx.y * 256 + colBase + tid] = s;
        stp[blockIdx.y * 256 + 128 + colBase + tid] = q;
    }
}

// ---------- GEMM B (BN finalize fused; ordered partial reduce; bf16 W) ----------
__global__ __launch_bounds__(256)
void gemm_b_kernel(const float* __restrict__ Hin, const float* __restrict__ stp,
                   int NR, const float* __restrict__ gam, const float* __restrict__ bet,
                   float invN, const unsigned short* __restrict__ Wb,
                   const float* __restrict__ bias, float* __restrict__ out) {
    __shared__ short Asm[4096];
    __shared__ short Bsm[2048];
    __shared__ float ssc[128], ssf[128];
    int tid = threadIdx.x;
    if (tid < 128) {
        float s = 0.f, q = 0.f;
        for (int r = 0; r < NR; ++r) {          // fixed order -> deterministic
            s += stp[r * 256 + tid];
            q += stp[r * 256 + 128 + tid];
        }
        float mu = s * invN;
        float var = q * invN - mu * mu;
        float rstd = rsqrtf(fmaxf(var, 0.f) + 1e-5f);
        float sc = rstd * gam[tid];
        ssc[tid] = sc;
        ssf[tid] = bet[tid] - mu * sc;
    }
    __syncthreads();
    int lane = tid & 63, w = tid >> 6;
    int m16 = lane & 15, quad = lane >> 4;
    int rowBase = blockIdx.y * 128;
    int colBase = blockIdx.x * 64;
    f32x4 acc[2][4] = {};
    for (int k0 = 0; k0 < 128; k0 += 32) {
        #pragma unroll
        for (int i = 0; i < 2; ++i) {
            int u = tid + i * 256;
            int r = u >> 2, g = u & 3;
            int c = k0 + g * 8;
            const float* p = &Hin[(rowBase + r) * 128 + c];
            float4 x = *(const float4*)p, y = *(const float4*)(p + 4);
            float h0 = fmaxf(x.x * ssc[c+0] + ssf[c+0], 0.f);
            float h1 = fmaxf(x.y * ssc[c+1] + ssf[c+1], 0.f);
            float h2 = fmaxf(x.z * ssc[c+2] + ssf[c+2], 0.f);
            float h3 = fmaxf(x.w * ssc[c+3] + ssf[c+3], 0.f);
            float h4 = fmaxf(y.x * ssc[c+4] + ssf[c+4], 0.f);
            float h5 = fmaxf(y.y * ssc[c+5] + ssf[c+5], 0.f);
            float h6 = fmaxf(y.z * ssc[c+6] + ssf[c+6], 0.f);
            float h7 = fmaxf(y.w * ssc[c+7] + ssf[c+7], 0.f);
            uint4 pk = make_uint4(pack2(h0, h1), pack2(h2, h3),
                                  pack2(h4, h5), pack2(h6, h7));
            int blk = (r >> 4) * 64 + (r & 15) * 4 + g;
            *(uint4*)&Asm[blk * 8] = pk;
        }
        {
            int n = tid >> 2, g = tid & 3;
            uint4 pk = *(const uint4*)&Wb[(size_t)(colBase + n) * 128 + k0 + g * 8];
            int blk = (n >> 4) * 64 + (n & 15) * 4 + g;
            *(uint4*)&Bsm[blk * 8] = pk;
        }
        __syncthreads();
        bf16x8 a0 = *(const bf16x8*)&Asm[((2 * w + 0) * 64 + m16 * 4 + quad) * 8];
        bf16x8 a1 = *(const bf16x8*)&Asm[((2 * w + 1) * 64 + m16 * 4 + quad) * 8];
        #pragma unroll
        for (int ct = 0; ct < 4; ++ct) {
            bf16x8 bf = *(const bf16x8*)&Bsm[(ct * 64 + m16 * 4 + quad) * 8];
            acc[0][ct] = __builtin_amdgcn_mfma_f32_16x16x32_bf16(a0, bf, acc[0][ct], 0, 0, 0);
            acc[1][ct] = __builtin_amdgcn_mfma_f32_16x16x32_bf16(a1, bf, acc[1][ct], 0, 0, 0);
        }
        __syncthreads();
    }
    #pragma unroll
    for (int ct = 0; ct < 4; ++ct) {
        float bv = bias[colBase + ct * 16 + m16];
        #pragma unroll
        for (int rt = 0; rt < 2; ++rt)
            #pragma unroll
            for (int r = 0; r < 4; ++r) {
                int row = rowBase + (2 * w + rt) * 16 + quad * 4 + r;
                out[row * 128 + colBase + ct * 16 + m16] = acc[rt][ct][r] + bv;
            }
    }
}

extern "C" void kernel_launch(void* const* d_in, const int* in_sizes, int n_in,
                              void* d_out, int out_size, void* d_ws, size_t ws_size,
                              hipStream_t stream) {
    const float* pts_r1 = (const float*)d_in[0];   // (2,8192,3)
    const float* pts_r2 = (const float*)d_in[1];   // (2,4096,3)
    const float* pts_r4 = (const float*)d_in[2];   // (2,2048,3)
    const float* feat0  = (const float*)d_in[3];   // (16384,128)
    const float* feat1  = (const float*)d_in[4];   // (8192,128)
    const float* feat2  = (const float*)d_in[5];   // (4096,128)
    const float* w3a = (const float*)d_in[6];      // (128,256)
    const float* g3  = (const float*)d_in[7];
    const float* b3  = (const float*)d_in[8];
    const float* w3b = (const float*)d_in[9];      // (128,128)
    const float* bb3 = (const float*)d_in[10];
    const float* w4a = (const float*)d_in[11];     // (128,256)
    const float* g4  = (const float*)d_in[12];
    const float* b4  = (const float*)d_in[13];
    const float* w4b = (const float*)d_in[14];     // (128,128)
    const float* bb4 = (const float*)d_in[15];

    float* wsf = (float*)d_ws;
    // ---- lifetimes (float offsets) ----
    float4* xyz1 = (float4*)(wsf + 0);          // [0, 65536)
    float4* xyz2 = (float4*)(wsf + 65536);      // [65536, 98304)
    float4* xyz4 = (float4*)(wsf + 98304);      // [98304, 114688)
    unsigned* f2ib = (unsigned*)(wsf + 114688); // bf16 8192x128 [114688, 638976)
    float* H1  = wsf + 638976;                  // [638976, 1687552)
    float* n3  = wsf + 1687552;                 // [1687552, 2736128)
    unsigned* n3ib = (unsigned*)(wsf + 114688); // bf16 16384x128 [114688,1163264)
                                                //   over f2ib+H1 (both dead)
    float* H2  = wsf + 2736128;                 // [2736128, 4833280)
    unsigned* f1b  = (unsigned*)(wsf + 2736128);// bf16 feat1 [2736128, 3260416)
                                                //   in H2 head (dead before H2)
    unsigned* w3ab = (unsigned*)(wsf + 4833280);// [4833280, 4849664)
    unsigned* w4ab = (unsigned*)(wsf + 4849664);// [4849664, 4866048)
    unsigned* w3bb = (unsigned*)(wsf + 4866048);// [4866048, 4874240)
    unsigned* w4bb = (unsigned*)(wsf + 4874240);// [4874240, 4882432)
    float* st1p = wsf + 4882432;                // 64*256  [4882432, 4898816)
    float* st2p = wsf + 4898816;                // 128*256 [4898816, 4931584)
    unsigned* f0b = (unsigned*)d_out;           // bf16 feat0 in d_out head
                                                //   (dead once gemm_b_f4 writes)

    // 1. prep: pad xyz + one-shot bf16 conversion of L-operands and weights
    prep_kernel<<<512, 256, 0, stream>>>(pts_r1, pts_r2, pts_r4,
                                         feat0, feat1, w3a, w4a, w3b, w4b,
                                         xyz1, xyz2, xyz4,
                                         f0b, f1b, w3ab, w4ab, w3bb, w4bb);
    // 2. interp #1: feat2 (fp32) on pts_r4 grid -> pts_r2 targets, bf16 out
    nn_interp_kernel<64><<<dim3(512, 2), 256, 0, stream>>>(xyz2, 4096, xyz4, 2048,
                                                           feat2, f2ib);
    // 3. fnode 3
    gemm_a_kernel<<<dim3(2, 64), 256, 0, stream>>>(
        (const unsigned short*)f1b, (const unsigned short*)f2ib,
        (const unsigned short*)w3ab, H1, st1p);
    gemm_b_kernel<<<dim3(2, 64), 256, 0, stream>>>(
        H1, st1p, 64, g3, b3, 1.f / 8192.f,
        (const unsigned short*)w3bb, bb3, n3);
    // 4. interp #2: n3 (fp32) on pts_r2 grid -> pts_r1 targets, bf16 out
    nn_interp_kernel<128><<<dim3(1024, 2), 256, 0, stream>>>(xyz1, 8192, xyz2, 4096,
                                                             n3, n3ib);
    // 5. fnode 4
    gemm_a_kernel<<<dim3(2, 128), 256, 0, stream>>>(
        (const unsigned short*)f0b, (const unsigned short*)n3ib,
        (const unsigned short*)w4ab, H2, st2p);
    gemm_b_kernel<<<dim3(2, 128), 256, 0, stream>>>(
        H2, st2p, 128, g4, b4, 1.f / 16384.f,
        (const unsigned short*)w4bb, bb4, (float*)d_out);
}